// Round 3
// baseline (395.661 us; speedup 1.0000x reference)
//
#include <hip/hip_runtime.h>

#define E   128
#define HD  32
#define NB  512
#define NN  65536
#define TT  (NB + NN)   // 66048 tokens: [0,NB) metal, [NB,TT) nodes
#define TE  ((size_t)TT * 128)

typedef __attribute__((ext_vector_type(8))) short short8;
typedef __attribute__((ext_vector_type(4))) float f32x4;

__device__ __forceinline__ const float* row_ptr(const float* base, const float* metal, int t) {
  return (t < NB) ? metal + (size_t)t * E : base + (size_t)(t - NB) * E;
}
__device__ __forceinline__ float* row_ptr_w(float* base, float* metal, int t) {
  return (t < NB) ? metal + (size_t)t * E : base + (size_t)(t - NB) * E;
}

__device__ __forceinline__ unsigned short f2bf_rne(float x) {
  unsigned u = __float_as_uint(x);
  return (unsigned short)((u + 0x7FFFu + ((u >> 16) & 1u)) >> 16);
}
__device__ __forceinline__ void split_bf(float x, unsigned short& h, unsigned short& l) {
  h = f2bf_rne(x);
  float hf = __uint_as_float(((unsigned)h) << 16);
  l = f2bf_rne(x - hf);
}

// start[b] = first node index of graph b (batch sorted); start[NB] = NN.
__global__ void k_starts(const int* __restrict__ batch, int* __restrict__ start) {
  int i = blockIdx.x * blockDim.x + threadIdx.x;
  if (i >= NN) return;
  int bi = batch[i];
  int bp = (i == 0) ? -1 : batch[i - 1];
  for (int b = bp + 1; b <= bi; ++b) start[b] = i;
  if (i == NN - 1)
    for (int b = bi + 1; b <= NB; ++b) start[b] = NN;
}

// seq row of token t: metal g -> start[g]+g ; node i -> i + batch[i] + 1
__global__ void k_seqmap(const int* __restrict__ batch, const int* __restrict__ start,
                         int* __restrict__ seqmap) {
  int t = blockIdx.x * 256 + threadIdx.x;
  if (t >= TT) return;
  seqmap[t] = (t < NB) ? (start[t] + t) : (t - NB + batch[t - NB] + 1);
}

// Split weights to hi/lo bf16. Rows: [0,128)Wq | [128,256)Wk | [256,640)in_w | [640,768)out_w
__global__ void k_wconv(const float* __restrict__ Wq, const float* __restrict__ Wk,
                        const float* __restrict__ in_w, const float* __restrict__ out_w,
                        unsigned short* __restrict__ Wh, unsigned short* __restrict__ Wl) {
  int idx = blockIdx.x * 256 + threadIdx.x;
  int r = idx >> 7, c = idx & 127;
  float v;
  if (r < 128)      v = Wq[r * 128 + c];
  else if (r < 256) v = Wk[(r - 128) * 128 + c];
  else if (r < 640) v = in_w[(r - 256) * 128 + c];
  else              v = out_w[(r - 640) * 128 + c];
  unsigned short h, l;
  split_bf(v, h, l);
  Wh[idx] = h;
  Wl[idx] = l;
}

// Fused chain, barrier-free: 64-row tile, 4 waves (wave owns 16 rows).
// All A/B MFMA fragments loaded DIRECTLY from global (A: 16-row x 128B panels,
// coalesced; W: L2-resident broadcast). Stage-1 H = relu(x@W1^T+b1) stays in
// registers; hand-off to stage-2 A-fragments via wave-private LDS transpose
// (same-wave LDS ops are in-order -> no __syncthreads anywhere).
// Optionally (WITH_V) also V = x@Wv^T + bv from the same A fragments.
template <bool WITH_V>
__global__ __launch_bounds__(256, WITH_V ? 3 : 4)
void k_fused(const float* __restrict__ Ax, const float* __restrict__ Am,
             const unsigned short* __restrict__ W1h, const unsigned short* __restrict__ W1l,
             const float* __restrict__ b1,
             const unsigned short* __restrict__ Wvh, const unsigned short* __restrict__ Wvl,
             const float* __restrict__ bv,
             const unsigned short* __restrict__ W2h, const unsigned short* __restrict__ W2l,
             const float* __restrict__ b2, float postscale,
             unsigned short* __restrict__ Voh,
             unsigned short* __restrict__ Oh, unsigned short* __restrict__ Ol,
             const int* __restrict__ seqmap) {
  __shared__ unsigned short AshH[64][40];   // 5120 B, wave-private rows
  __shared__ unsigned short AshL[64][40];   // 5120 B

  const int tid = threadIdx.x;
  const int wave = tid >> 6;
  const int lane = tid & 63;
  const int lrow = lane & 15;
  const int q = lane >> 4;
  const int t0 = blockIdx.x * 64;

  // A-row pointer (uniform branch: blocks 0..7 all-metal, others all-node)
  const float* rp = row_ptr(Ax, Am, t0 + wave * 16 + lrow);

  f32x4 acc1[8], accv[8];
  #pragma unroll
  for (int nt = 0; nt < 8; ++nt) {
    acc1[nt] = (f32x4){0.f, 0.f, 0.f, 0.f};
    if (WITH_V) accv[nt] = (f32x4){0.f, 0.f, 0.f, 0.f};
  }

  // ---- stage 1: x -> acc1 (H pre-act) [+ accv], no LDS, no barriers ----
  for (int ks = 0; ks < 4; ++ks) {
    float4 f0 = *(const float4*)(rp + ks * 32 + q * 8);
    float4 f1 = *(const float4*)(rp + ks * 32 + q * 8 + 4);
    short8 ah, al;
    {
      unsigned short h, l;
      split_bf(f0.x, h, l); ah[0] = (short)h; al[0] = (short)l;
      split_bf(f0.y, h, l); ah[1] = (short)h; al[1] = (short)l;
      split_bf(f0.z, h, l); ah[2] = (short)h; al[2] = (short)l;
      split_bf(f0.w, h, l); ah[3] = (short)h; al[3] = (short)l;
      split_bf(f1.x, h, l); ah[4] = (short)h; al[4] = (short)l;
      split_bf(f1.y, h, l); ah[5] = (short)h; al[5] = (short)l;
      split_bf(f1.z, h, l); ah[6] = (short)h; al[6] = (short)l;
      split_bf(f1.w, h, l); ah[7] = (short)h; al[7] = (short)l;
    }
    #pragma unroll
    for (int nt = 0; nt < 8; ++nt) {
      size_t wo = (size_t)(nt * 16 + lrow) * 128 + ks * 32 + q * 8;
      short8 bh = *(const short8*)(W1h + wo);
      short8 bl = *(const short8*)(W1l + wo);
      acc1[nt] = __builtin_amdgcn_mfma_f32_16x16x32_bf16(ah, bh, acc1[nt], 0, 0, 0);
      acc1[nt] = __builtin_amdgcn_mfma_f32_16x16x32_bf16(al, bh, acc1[nt], 0, 0, 0);
      acc1[nt] = __builtin_amdgcn_mfma_f32_16x16x32_bf16(ah, bl, acc1[nt], 0, 0, 0);
      if (WITH_V) {
        short8 ch = *(const short8*)(Wvh + wo);
        short8 cl = *(const short8*)(Wvl + wo);
        accv[nt] = __builtin_amdgcn_mfma_f32_16x16x32_bf16(ah, ch, accv[nt], 0, 0, 0);
        accv[nt] = __builtin_amdgcn_mfma_f32_16x16x32_bf16(al, ch, accv[nt], 0, 0, 0);
        accv[nt] = __builtin_amdgcn_mfma_f32_16x16x32_bf16(ah, cl, accv[nt], 0, 0, 0);
      }
    }
  }

  // ---- V epilogue (bf16 seq order) ----
  if (WITH_V) {
    float bvv[8];
    #pragma unroll
    for (int nt = 0; nt < 8; ++nt) bvv[nt] = bv[nt * 16 + lrow];
    #pragma unroll
    for (int reg = 0; reg < 4; ++reg) {
      int t = t0 + wave * 16 + q * 4 + reg;
      size_t ro = (size_t)seqmap[t] * 128;
      #pragma unroll
      for (int nt = 0; nt < 8; ++nt)
        Voh[ro + nt * 16 + lrow] = f2bf_rne(accv[nt][reg] + bvv[nt]);
    }
  }

  // ---- stage 2: O = (relu(acc1 + b1) @ W2^T + b2) * postscale ----
  f32x4 acc2[8];
  #pragma unroll
  for (int nt = 0; nt < 8; ++nt) acc2[nt] = (f32x4){0.f, 0.f, 0.f, 0.f};
  float b1v[8];
  #pragma unroll
  for (int nt = 0; nt < 8; ++nt) b1v[nt] = b1[nt * 16 + lrow];

  #pragma unroll
  for (int ks2 = 0; ks2 < 4; ++ks2) {
    // H k-slice: registers (C/D layout) -> wave-private LDS A-slice (split hi/lo)
    #pragma unroll
    for (int n2 = 0; n2 < 2; ++n2) {
      const int nt = ks2 * 2 + n2;
      #pragma unroll
      for (int reg = 0; reg < 4; ++reg) {
        int row = wave * 16 + q * 4 + reg;
        float v = fmaxf(acc1[nt][reg] + b1v[nt], 0.f);
        unsigned short h, l;
        split_bf(v, h, l);
        AshH[row][n2 * 16 + lrow] = h;
        AshL[row][n2 * 16 + lrow] = l;
      }
    }
    short8 ah = *(const short8*)&AshH[wave * 16 + lrow][q * 8];
    short8 al = *(const short8*)&AshL[wave * 16 + lrow][q * 8];
    #pragma unroll
    for (int nt = 0; nt < 8; ++nt) {
      size_t wo = (size_t)(nt * 16 + lrow) * 128 + ks2 * 32 + q * 8;
      short8 bh = *(const short8*)(W2h + wo);
      short8 bl = *(const short8*)(W2l + wo);
      acc2[nt] = __builtin_amdgcn_mfma_f32_16x16x32_bf16(ah, bh, acc2[nt], 0, 0, 0);
      acc2[nt] = __builtin_amdgcn_mfma_f32_16x16x32_bf16(al, bh, acc2[nt], 0, 0, 0);
      acc2[nt] = __builtin_amdgcn_mfma_f32_16x16x32_bf16(ah, bl, acc2[nt], 0, 0, 0);
    }
  }

  // ---- O epilogue (split-bf16, seq order) ----
  float b2v[8];
  #pragma unroll
  for (int nt = 0; nt < 8; ++nt) b2v[nt] = b2[nt * 16 + lrow];
  #pragma unroll
  for (int reg = 0; reg < 4; ++reg) {
    int t = t0 + wave * 16 + q * 4 + reg;
    size_t ro = (size_t)seqmap[t] * 128;
    #pragma unroll
    for (int nt = 0; nt < 8; ++nt) {
      float v = (acc2[nt][reg] + b2v[nt]) * postscale;
      unsigned short h, l;
      split_bf(v, h, l);
      Oh[ro + nt * 16 + lrow] = h;
      Ol[ro + nt * 16 + lrow] = l;
    }
  }
}

// out = ctx@out_w^T + b, A gathered via seqmap. Barrier-free, LDS-free,
// direct global fragment loads. 64-row tile, 4 waves.
__global__ __launch_bounds__(256, 4)
void k_outproj(const float* __restrict__ ctx, const int* __restrict__ seqmap,
               const unsigned short* __restrict__ Wh, const unsigned short* __restrict__ Wl,
               const float* __restrict__ bias,
               float* __restrict__ Cx, float* __restrict__ Cm) {
  const int tid = threadIdx.x;
  const int wave = tid >> 6;
  const int lane = tid & 63;
  const int lrow = lane & 15;
  const int q = lane >> 4;
  const int t0 = blockIdx.x * 64;

  const float* rp = ctx + (size_t)seqmap[t0 + wave * 16 + lrow] * 128;

  f32x4 acc[8];
  #pragma unroll
  for (int nt = 0; nt < 8; ++nt) acc[nt] = (f32x4){0.f, 0.f, 0.f, 0.f};

  for (int ks = 0; ks < 4; ++ks) {
    float4 f0 = *(const float4*)(rp + ks * 32 + q * 8);
    float4 f1 = *(const float4*)(rp + ks * 32 + q * 8 + 4);
    short8 ah, al;
    {
      unsigned short h, l;
      split_bf(f0.x, h, l); ah[0] = (short)h; al[0] = (short)l;
      split_bf(f0.y, h, l); ah[1] = (short)h; al[1] = (short)l;
      split_bf(f0.z, h, l); ah[2] = (short)h; al[2] = (short)l;
      split_bf(f0.w, h, l); ah[3] = (short)h; al[3] = (short)l;
      split_bf(f1.x, h, l); ah[4] = (short)h; al[4] = (short)l;
      split_bf(f1.y, h, l); ah[5] = (short)h; al[5] = (short)l;
      split_bf(f1.z, h, l); ah[6] = (short)h; al[6] = (short)l;
      split_bf(f1.w, h, l); ah[7] = (short)h; al[7] = (short)l;
    }
    #pragma unroll
    for (int nt = 0; nt < 8; ++nt) {
      size_t wo = (size_t)(nt * 16 + lrow) * 128 + ks * 32 + q * 8;
      short8 bh = *(const short8*)(Wh + wo);
      short8 bl = *(const short8*)(Wl + wo);
      acc[nt] = __builtin_amdgcn_mfma_f32_16x16x32_bf16(ah, bh, acc[nt], 0, 0, 0);
      acc[nt] = __builtin_amdgcn_mfma_f32_16x16x32_bf16(al, bh, acc[nt], 0, 0, 0);
      acc[nt] = __builtin_amdgcn_mfma_f32_16x16x32_bf16(ah, bl, acc[nt], 0, 0, 0);
    }
  }

  float bb[8];
  #pragma unroll
  for (int nt = 0; nt < 8; ++nt) bb[nt] = bias[nt * 16 + lrow];
  #pragma unroll
  for (int reg = 0; reg < 4; ++reg) {
    int t = t0 + wave * 16 + q * 4 + reg;
    float* cp = row_ptr_w(Cx, Cm, t);
    #pragma unroll
    for (int nt = 0; nt < 8; ++nt)
      cp[nt * 16 + lrow] = acc[nt][reg] + bb[nt];
  }
}

// Flash attention, swapped-operand form: grid (NB, 6), 4 waves = 4 heads, 32 q/block.
// S^T = mfma(K, Q): lane holds query = lane&15, keys = s*16 + quad*4 + r4.
// Softmax reduce over keys = 7 in-lane ops + 2 shfl (xor16, xor32).
// P -> PV B-frag transpose via packed u32 LDS (b64 writes, b128 reads).
// PV: O^T = mfma(A=V^T, B=P); ctx stored as aligned float4 per dim-quad.
__global__ __launch_bounds__(256, 4)
void k_flash(const unsigned short* __restrict__ Qh, const unsigned short* __restrict__ Ql,
             const unsigned short* __restrict__ Kh, const unsigned short* __restrict__ Kl,
             const unsigned short* __restrict__ Vb, const int* __restrict__ start,
             float* __restrict__ ctx) {
  __shared__ unsigned short Vlds[32][134];            // 8576 B, odd-word row stride
  __shared__ alignas(16) unsigned PtH[4][32][20];     // [wave][query][key-pair] 10240 B
  __shared__ alignas(16) unsigned PtL[4][32][20];     // 10240 B
  const int g = blockIdx.x;
  const int tid = threadIdx.x;
  const int wv = tid >> 6;        // head
  const int lane = tid & 63;
  const int lrow = lane & 15;
  const int quad = lane >> 4;
  const int s0 = start[g];
  const int c = start[g + 1] - s0 + 1;   // slots incl. metal at 0
  const int sbase = s0 + g;
  const int hoff = wv * 32 + quad * 8;   // k-dim offset for frags

  for (int qb = 32 * blockIdx.y; qb < c; qb += 32 * gridDim.y) {
    short8 qfh[2], qfl[2];
    #pragma unroll
    for (int mt = 0; mt < 2; ++mt) {
      int qs = qb + mt * 16 + lrow; if (qs >= c) qs = 0;
      size_t off = (size_t)(sbase + qs) * 128 + hoff;
      qfh[mt] = *(const short8*)(Qh + off);
      qfl[mt] = *(const short8*)(Ql + off);
    }
    float mr[2], lr[2];
    f32x4 O[2][2];   // [mt][nt]: O^T tile, lane: query=lrow, dim=nt*16+quad*4+reg
    #pragma unroll
    for (int mt = 0; mt < 2; ++mt) {
      mr[mt] = -3.0e38f; lr[mt] = 0.f;
      O[mt][0] = (f32x4){0.f, 0.f, 0.f, 0.f};
      O[mt][1] = (f32x4){0.f, 0.f, 0.f, 0.f};
    }

    const int nch = (c + 31) >> 5;
    for (int ch = 0; ch < nch; ++ch) {
      const int kb = ch * 32;
      // K A-frags from global (row = key = lane&15)
      short8 kfh[2], kfl[2];
      #pragma unroll
      for (int s = 0; s < 2; ++s) {
        int ks = kb + s * 16 + lrow; if (ks >= c) ks = 0;
        size_t off = (size_t)(sbase + ks) * 128 + hoff;
        kfh[s] = *(const short8*)(Kh + off);
        kfl[s] = *(const short8*)(Kl + off);
      }
      __syncthreads();   // previous chunk's Vlds reads complete
      // stage V chunk (32 keys x 128 dims bf16), row-major, odd-word stride
      #pragma unroll
      for (int r = 0; r < 2; ++r) {
        int key = r * 16 + (tid >> 4);
        int seg = tid & 15;
        int ks = kb + key; if (ks >= c) ks = 0;
        uint4 v = *(const uint4*)(Vb + (size_t)(sbase + ks) * 128 + seg * 8);
        unsigned* dst = (unsigned*)&Vlds[key][seg * 8];   // 4B-aligned
        dst[0] = v.x; dst[1] = v.y; dst[2] = v.z; dst[3] = v.w;
      }
      __syncthreads();

      // S^T = K Q^T (split-bf16, 3 MFMA per tile). sv[mt][s]: rows=keys, cols=queries
      f32x4 sv[2][2];
      #pragma unroll
      for (int mt = 0; mt < 2; ++mt)
        #pragma unroll
        for (int s = 0; s < 2; ++s) {
          f32x4 z = (f32x4){0.f, 0.f, 0.f, 0.f};
          z = __builtin_amdgcn_mfma_f32_16x16x32_bf16(kfh[s], qfh[mt], z, 0, 0, 0);
          z = __builtin_amdgcn_mfma_f32_16x16x32_bf16(kfl[s], qfh[mt], z, 0, 0, 0);
          z = __builtin_amdgcn_mfma_f32_16x16x32_bf16(kfh[s], qfl[mt], z, 0, 0, 0);
          sv[mt][s] = z;
        }

      #pragma unroll
      for (int mt = 0; mt < 2; ++mt) {
        // mask + in-lane max over 8 keys held by this lane
        float m8 = mr[mt];
        #pragma unroll
        for (int s = 0; s < 2; ++s)
          #pragma unroll
          for (int r4 = 0; r4 < 4; ++r4) {
            bool valid = (kb + s * 16 + quad * 4 + r4) < c;
            float v = valid ? sv[mt][s][r4] : -3.0e38f;
            sv[mt][s][r4] = v;
            m8 = fmaxf(m8, v);
          }
        m8 = fmaxf(m8, __shfl_xor(m8, 16));
        m8 = fmaxf(m8, __shfl_xor(m8, 32));
        float al = exp2f(mr[mt] - m8);
        mr[mt] = m8;

        float p[2][4];
        float rs = 0.f;
        #pragma unroll
        for (int s = 0; s < 2; ++s)
          #pragma unroll
          for (int r4 = 0; r4 < 4; ++r4) {
            p[s][r4] = exp2f(sv[mt][s][r4] - m8);
            rs += p[s][r4];
          }
        rs += __shfl_xor(rs, 16);
        rs += __shfl_xor(rs, 32);
        lr[mt] = lr[mt] * al + rs;

        // split + pack + store P^T (wave-private; same-wave read below)
        const int Q = mt * 16 + lrow;
        #pragma unroll
        for (int s = 0; s < 2; ++s) {
          unsigned short h0, l0, h1, l1, h2, l2, h3, l3;
          split_bf(p[s][0], h0, l0); split_bf(p[s][1], h1, l1);
          split_bf(p[s][2], h2, l2); split_bf(p[s][3], h3, l3);
          uint2 hw, lw;
          hw.x = (unsigned)h0 | ((unsigned)h1 << 16);
          hw.y = (unsigned)h2 | ((unsigned)h3 << 16);
          lw.x = (unsigned)l0 | ((unsigned)l1 << 16);
          lw.y = (unsigned)l2 | ((unsigned)l3 << 16);
          *(uint2*)&PtH[wv][Q][s * 8 + quad * 2] = hw;
          *(uint2*)&PtL[wv][Q][s * 8 + quad * 2] = lw;
        }
        // O rescale
        #pragma unroll
        for (int nt = 0; nt < 2; ++nt)
          #pragma unroll
          for (int r4 = 0; r4 < 4; ++r4)
            O[mt][nt][r4] *= al;
      }

      // V A-frags (transposed Vlds access): A[dim][key], row=dim=lane&15
      short8 vf[2];
      #pragma unroll
      for (int nt = 0; nt < 2; ++nt)
        #pragma unroll
        for (int jj = 0; jj < 8; ++jj)
          vf[nt][jj] = (short)Vlds[quad * 8 + jj][wv * 32 + nt * 16 + lrow];

      // PV: O^T += V^T (Ph + Pl)
      #pragma unroll
      for (int mt = 0; mt < 2; ++mt) {
        short8 bh = *(const short8*)&PtH[wv][mt * 16 + lrow][quad * 4];
        short8 bl = *(const short8*)&PtL[wv][mt * 16 + lrow][quad * 4];
        #pragma unroll
        for (int nt = 0; nt < 2; ++nt) {
          O[mt][nt] = __builtin_amdgcn_mfma_f32_16x16x32_bf16(vf[nt], bh, O[mt][nt], 0, 0, 0);
          O[mt][nt] = __builtin_amdgcn_mfma_f32_16x16x32_bf16(vf[nt], bl, O[mt][nt], 0, 0, 0);
        }
      }
    }

    // store ctx (fp32, seq order). Lane: query = lrow, dims = nt*16 + quad*4 + r4
    #pragma unroll
    for (int mt = 0; mt < 2; ++mt) {
      int qs = qb + mt * 16 + lrow;
      if (qs < c) {
        float inv = 1.f / lr[mt];
        float* cp = ctx + (size_t)(sbase + qs) * 128 + wv * 32 + quad * 4;
        float4 o0, o1;
        o0.x = O[mt][0][0] * inv; o0.y = O[mt][0][1] * inv;
        o0.z = O[mt][0][2] * inv; o0.w = O[mt][0][3] * inv;
        o1.x = O[mt][1][0] * inv; o1.y = O[mt][1][1] * inv;
        o1.z = O[mt][1][2] * inv; o1.w = O[mt][1][3] * inv;
        *(float4*)cp = o0;
        *(float4*)(cp + 16) = o1;
      }
    }
  }
}

extern "C" void kernel_launch(void* const* d_in, const int* in_sizes, int n_in,
                              void* d_out, int out_size, void* d_ws, size_t ws_size,
                              hipStream_t stream) {
  const float* x       = (const float*)d_in[0];
  const float* metal_x = (const float*)d_in[1];
  const int*   batch   = (const int*)d_in[2];
  const float* Wk      = (const float*)d_in[3];
  const float* bk      = (const float*)d_in[4];
  const float* Wq      = (const float*)d_in[5];
  const float* bq      = (const float*)d_in[6];
  const float* in_w    = (const float*)d_in[7];
  const float* in_b    = (const float*)d_in[8];
  const float* out_w   = (const float*)d_in[9];
  const float* out_b   = (const float*)d_in[10];
  float* out = (float*)d_out;

  // ---- workspace layout (float offsets) ----
  // [0,528)            start (513 ints, padded)
  // [528,66576)        seqmap (66048 ints)
  // [66576,164880)     Wh+Wl  (2 x 98304 shorts)
  // [164880, ...)      big buffers
  float* ws = (float*)d_ws;
  int* start  = (int*)d_ws;
  int* seqmap = (int*)(ws + 528);
  unsigned short* Wh = (unsigned short*)(ws + 66576);
  unsigned short* Wl = Wh + 768 * 128;
  const size_t BUF0 = 164880;
  float* ctx = ws + BUF0;                                        // TE floats
  unsigned short* Qsh = (unsigned short*)(ws + BUF0 + TE);
  unsigned short* Qsl = Qsh + TE;
  unsigned short* Ksh = (unsigned short*)(ws + BUF0 + 2 * TE);
  unsigned short* Ksl = Ksh + TE;
  unsigned short* Vsb = (unsigned short*)(ws + BUF0 + 3 * TE);   // bf16 only
  // peak ws = (164880 + 3.5*TE)*4 B ~= 119.0 MB (unchanged from known-good)

  k_starts<<<NN / 256, 256, 0, stream>>>(batch, start);
  k_seqmap<<<TT / 256, 256, 0, stream>>>(batch, start, seqmap);
  k_wconv<<<768 * 128 / 256, 256, 0, stream>>>(Wq, Wk, in_w, out_w, Wh, Wl);

  const int gb = TT / 64;  // 1032
  const float SCL2 = 0.17677669529663687f * 1.4426950408889634f;  // scale*log2(e)

  // x -> {V (bf16 seq), Hq -> Q (split seq, scaled)} in one pass over x
  k_fused<true><<<gb, 256, 0, stream>>>(
      x, metal_x,
      Wh, Wl, bq,                                  // W1 = Wq (relu)
      Wh + 512 * 128, Wl + 512 * 128, in_b + 2 * E, // Wv / bv
      Wh + 256 * 128, Wl + 256 * 128, in_b, SCL2,   // W2 = in_w q-proj
      Vsb, Qsh, Qsl, seqmap);
  // x -> Hk -> K (split seq)
  k_fused<false><<<gb, 256, 0, stream>>>(
      x, metal_x,
      Wh + 128 * 128, Wl + 128 * 128, bk,           // W1 = Wk (relu)
      nullptr, nullptr, nullptr,
      Wh + 384 * 128, Wl + 384 * 128, in_b + 128, 1.f, // W2 = in_w k-proj
      nullptr, Ksh, Ksl, seqmap);

  dim3 agrid(NB, 6);
  k_flash<<<agrid, 256, 0, stream>>>(Qsh, Qsl, Ksh, Ksl, Vsb, start, ctx);

  // out = ctx@out_w^T + b (A gathered via seqmap), token-order output
  k_outproj<<<gb, 256, 0, stream>>>(
      ctx, seqmap, Wh + 640 * 128, Wl + 640 * 128,
      out_b, out, out + (size_t)NN * E);
}

// Round 4
// 332.767 us; speedup vs baseline: 1.1890x; 1.1890x over previous
//
#include <hip/hip_runtime.h>

#define E   128
#define HD  32
#define NB  512
#define NN  65536
#define TT  (NB + NN)   // 66048 tokens: [0,NB) metal, [NB,TT) nodes
#define TE  ((size_t)TT * 128)

typedef __attribute__((ext_vector_type(8))) short short8;
typedef __attribute__((ext_vector_type(4))) float f32x4;

enum { AF32 = 0, ASPLIT = 1 };
enum { OF32T = 0, OSPLITT = 1, OSPLITSEQ = 2, OBF16SEQ = 3 };

__device__ __forceinline__ const float* row_ptr(const float* base, const float* metal, int t) {
  return (t < NB) ? metal + (size_t)t * E : base + (size_t)(t - NB) * E;
}
__device__ __forceinline__ float* row_ptr_w(float* base, float* metal, int t) {
  return (t < NB) ? metal + (size_t)t * E : base + (size_t)(t - NB) * E;
}

__device__ __forceinline__ unsigned short f2bf_rne(float x) {
  unsigned u = __float_as_uint(x);
  return (unsigned short)((u + 0x7FFFu + ((u >> 16) & 1u)) >> 16);
}
__device__ __forceinline__ void split_bf(float x, unsigned short& h, unsigned short& l) {
  h = f2bf_rne(x);
  float hf = __uint_as_float(((unsigned)h) << 16);
  l = f2bf_rne(x - hf);
}

// start[b] = first node index of graph b (batch sorted); start[NB] = NN.
__global__ void k_starts(const int* __restrict__ batch, int* __restrict__ start) {
  int i = blockIdx.x * blockDim.x + threadIdx.x;
  if (i >= NN) return;
  int bi = batch[i];
  int bp = (i == 0) ? -1 : batch[i - 1];
  for (int b = bp + 1; b <= bi; ++b) start[b] = i;
  if (i == NN - 1)
    for (int b = bi + 1; b <= NB; ++b) start[b] = NN;
}

// seq row of token t: metal g -> start[g]+g ; node i -> i + batch[i] + 1
__global__ void k_seqmap(const int* __restrict__ batch, const int* __restrict__ start,
                         int* __restrict__ seqmap) {
  int t = blockIdx.x * 256 + threadIdx.x;
  if (t >= TT) return;
  seqmap[t] = (t < NB) ? (start[t] + t) : (t - NB + batch[t - NB] + 1);
}

// Split weights to hi/lo bf16. Rows: [0,128)Wq | [128,256)Wk | [256,640)in_w | [640,768)out_w
__global__ void k_wconv(const float* __restrict__ Wq, const float* __restrict__ Wk,
                        const float* __restrict__ in_w, const float* __restrict__ out_w,
                        unsigned short* __restrict__ Wh, unsigned short* __restrict__ Wl) {
  int idx = blockIdx.x * 256 + threadIdx.x;
  int r = idx >> 7, c = idx & 127;
  float v;
  if (r < 128)      v = Wq[r * 128 + c];
  else if (r < 256) v = Wk[(r - 128) * 128 + c];
  else if (r < 640) v = in_w[(r - 256) * 128 + c];
  else              v = out_w[(r - 640) * 128 + c];
  unsigned short h, l;
  split_bf(v, h, l);
  Wh[idx] = h;
  Wl[idx] = l;
}

// C = act(A @ W^T + b) [* postscale] via split-bf16 MFMA. 128x128 tile, 4 waves.
// (Used only for the out-projection now.)
template <int AM, int OM, bool RELU>
__global__ __launch_bounds__(256, 2)
void k_gemm(const float* __restrict__ Ax, const float* __restrict__ Am,
            const int* __restrict__ rowmap,
            const unsigned short* __restrict__ Ah, const unsigned short* __restrict__ Al,
            const unsigned short* __restrict__ Wh, const unsigned short* __restrict__ Wl,
            const float* __restrict__ bias, float postscale,
            float* __restrict__ Cx, float* __restrict__ Cm,
            unsigned short* __restrict__ Oh, unsigned short* __restrict__ Ol,
            const int* __restrict__ seqmap) {
  __shared__ char smem[40960];
  float (*Afl)[36] = (float (*)[36])smem;                               // 18432 B (AF32)
  unsigned short (*AshH)[40] = (unsigned short (*)[40])smem;            // 10240 B (ASPLIT)
  unsigned short (*AshL)[40] = (unsigned short (*)[40])(smem + 10240);  // 10240 B
  unsigned short (*WldsH)[40] = (unsigned short (*)[40])(smem + 20480);
  unsigned short (*WldsL)[40] = (unsigned short (*)[40])(smem + 30720);

  const int tid = threadIdx.x;
  const int wave = tid >> 6;
  const int lane = tid & 63;
  const int lrow = lane & 15;
  const int q = lane >> 4;
  const int t0 = blockIdx.x * 128;

  f32x4 acc[2][8];
  #pragma unroll
  for (int mt = 0; mt < 2; ++mt)
    #pragma unroll
    for (int nt = 0; nt < 8; ++nt) acc[mt][nt] = (f32x4){0.f, 0.f, 0.f, 0.f};

  for (int ks = 0; ks < 4; ++ks) {
    __syncthreads();
    if (AM == AF32) {
      #pragma unroll
      for (int u = 0; u < 4; ++u) {
        int e4 = tid + u * 256;
        int m = e4 >> 3, k4 = e4 & 7;
        const float* rp = rowmap ? Ax + (size_t)rowmap[t0 + m] * E
                                 : row_ptr(Ax, Am, t0 + m);
        float4 v = ((const float4*)(rp + ks * 32))[k4];
        *(float4*)&Afl[m][k4 * 4] = v;
      }
    } else {
      #pragma unroll
      for (int u = 0; u < 2; ++u) {
        int e = tid + u * 256;        // [0,512)
        int row = e >> 2, seg = e & 3;
        size_t go = (size_t)(t0 + row) * 128 + ks * 32 + seg * 8;
        *(short8*)&AshH[row][seg * 8] = *(const short8*)(Ah + go);
        *(short8*)&AshL[row][seg * 8] = *(const short8*)(Al + go);
      }
    }
    // W hi/lo slices
    #pragma unroll
    for (int u = 0; u < 4; ++u) {
      int idx = tid + u * 256;
      int half = idx >> 9, rem = idx & 511;
      int j = rem >> 2, seg = rem & 3;
      const unsigned short* src = (half ? Wl : Wh) + j * 128 + ks * 32 + seg * 8;
      short8 v = *(const short8*)src;
      unsigned short* dst = (half ? &WldsL[j][seg * 8] : &WldsH[j][seg * 8]);
      *(short8*)dst = v;
    }
    __syncthreads();

    short8 ah[2], al[2];
    if (AM == AF32) {
      #pragma unroll
      for (int mt = 0; mt < 2; ++mt) {
        int m = wave * 32 + mt * 16 + lrow;
        float4 f0 = *(const float4*)&Afl[m][q * 8];
        float4 f1 = *(const float4*)&Afl[m][q * 8 + 4];
        unsigned short h, l;
        split_bf(f0.x, h, l); ah[mt][0] = (short)h; al[mt][0] = (short)l;
        split_bf(f0.y, h, l); ah[mt][1] = (short)h; al[mt][1] = (short)l;
        split_bf(f0.z, h, l); ah[mt][2] = (short)h; al[mt][2] = (short)l;
        split_bf(f0.w, h, l); ah[mt][3] = (short)h; al[mt][3] = (short)l;
        split_bf(f1.x, h, l); ah[mt][4] = (short)h; al[mt][4] = (short)l;
        split_bf(f1.y, h, l); ah[mt][5] = (short)h; al[mt][5] = (short)l;
        split_bf(f1.z, h, l); ah[mt][6] = (short)h; al[mt][6] = (short)l;
        split_bf(f1.w, h, l); ah[mt][7] = (short)h; al[mt][7] = (short)l;
      }
    } else {
      #pragma unroll
      for (int mt = 0; mt < 2; ++mt) {
        int m = wave * 32 + mt * 16 + lrow;
        ah[mt] = *(const short8*)&AshH[m][q * 8];
        al[mt] = *(const short8*)&AshL[m][q * 8];
      }
    }

    #pragma unroll
    for (int nt = 0; nt < 8; ++nt) {
      int j = nt * 16 + lrow;
      short8 bh = *(const short8*)&WldsH[j][q * 8];
      short8 bl = *(const short8*)&WldsL[j][q * 8];
      #pragma unroll
      for (int mt = 0; mt < 2; ++mt) {
        acc[mt][nt] = __builtin_amdgcn_mfma_f32_16x16x32_bf16(ah[mt], bh, acc[mt][nt], 0, 0, 0);
        acc[mt][nt] = __builtin_amdgcn_mfma_f32_16x16x32_bf16(al[mt], bh, acc[mt][nt], 0, 0, 0);
        acc[mt][nt] = __builtin_amdgcn_mfma_f32_16x16x32_bf16(ah[mt], bl, acc[mt][nt], 0, 0, 0);
      }
    }
  }

  // Epilogue. C/D layout: col = lane&15, row = q*4 + reg.
  #pragma unroll
  for (int mt = 0; mt < 2; ++mt) {
    #pragma unroll
    for (int reg = 0; reg < 4; ++reg) {
      int t = t0 + wave * 32 + mt * 16 + q * 4 + reg;
      float* cp = nullptr;
      size_t ro = 0;
      if (OM == OF32T) cp = row_ptr_w(Cx, Cm, t);
      else if (OM == OSPLITT) ro = (size_t)t * 128;
      else ro = (size_t)seqmap[t] * 128;
      #pragma unroll
      for (int nt = 0; nt < 8; ++nt) {
        int j = nt * 16 + lrow;
        float v = acc[mt][nt][reg] + bias[j];
        if (RELU) v = fmaxf(v, 0.f);
        v *= postscale;
        if (OM == OF32T) {
          cp[j] = v;
        } else if (OM == OBF16SEQ) {
          Oh[ro + j] = f2bf_rne(v);
        } else {
          unsigned short h, l;
          split_bf(v, h, l);
          Oh[ro + j] = h;
          Ol[ro + j] = l;
        }
      }
    }
  }
}

// Fused chain: H = relu(x@W1^T + b1) kept in registers; O = (H@W2^T + b2)*postscale
// written split-bf16 seq-order. Optionally (WITH_V) also V = x@Wv^T + bv, computed by
// time-sharing ONE W-LDS buffer per k-slice (stage W1 -> acc1 MFMAs -> barrier ->
// stage Wv into same buffer -> accv MFMAs from retained register A-frags).
// LDS = 40960 B -> 4 blocks/CU; __launch_bounds__(256,4) caps VGPR at 128.
template <bool WITH_V>
__global__ __launch_bounds__(256, 4)
void k_fused(const float* __restrict__ Ax, const float* __restrict__ Am,
             const unsigned short* __restrict__ W1h, const unsigned short* __restrict__ W1l,
             const float* __restrict__ b1,
             const unsigned short* __restrict__ Wvh, const unsigned short* __restrict__ Wvl,
             const float* __restrict__ bv,
             const unsigned short* __restrict__ W2h, const unsigned short* __restrict__ W2l,
             const float* __restrict__ b2, float postscale,
             unsigned short* __restrict__ Voh,
             unsigned short* __restrict__ Oh, unsigned short* __restrict__ Ol,
             const int* __restrict__ seqmap) {
  __shared__ char smem[40960];
  // stage-1 overlay
  float (*Afl)[36] = (float (*)[36])smem;                                   // 18432 B
  unsigned short (*WldsH)[40] = (unsigned short (*)[40])(smem + 18432);     // 10240 B
  unsigned short (*WldsL)[40] = (unsigned short (*)[40])(smem + 28672);     // 10240 B
  // stage-2 overlay (separated from stage-1 by __syncthreads)
  unsigned short (*AshH)[40] = (unsigned short (*)[40])smem;
  unsigned short (*AshL)[40] = (unsigned short (*)[40])(smem + 10240);
  unsigned short (*W2ldsH)[40] = (unsigned short (*)[40])(smem + 20480);
  unsigned short (*W2ldsL)[40] = (unsigned short (*)[40])(smem + 30720);

  const int tid = threadIdx.x;
  const int wave = tid >> 6;
  const int lane = tid & 63;
  const int lrow = lane & 15;
  const int q = lane >> 4;
  const int t0 = blockIdx.x * 128;

  f32x4 acc1[2][8];
  f32x4 accv[2][8];
  #pragma unroll
  for (int mt = 0; mt < 2; ++mt)
    #pragma unroll
    for (int nt = 0; nt < 8; ++nt) {
      acc1[mt][nt] = (f32x4){0.f, 0.f, 0.f, 0.f};
      if (WITH_V) accv[mt][nt] = (f32x4){0.f, 0.f, 0.f, 0.f};
    }

  // ---- stage 1: x tile -> acc1 (H pre-act) [+ accv] ----
  for (int ks = 0; ks < 4; ++ks) {
    __syncthreads();
    #pragma unroll
    for (int u = 0; u < 4; ++u) {
      int e4 = tid + u * 256;
      int m = e4 >> 3, k4 = e4 & 7;
      const float* rp = row_ptr(Ax, Am, t0 + m);
      float4 v = ((const float4*)(rp + ks * 32))[k4];
      *(float4*)&Afl[m][k4 * 4] = v;
    }
    #pragma unroll
    for (int u = 0; u < 4; ++u) {
      int idx = tid + u * 256;
      int half = idx >> 9, rem = idx & 511;
      int j = rem >> 2, seg = rem & 3;
      const unsigned short* src = (half ? W1l : W1h) + j * 128 + ks * 32 + seg * 8;
      short8 v = *(const short8*)src;
      unsigned short* dst = (half ? &WldsL[j][seg * 8] : &WldsH[j][seg * 8]);
      *(short8*)dst = v;
    }
    __syncthreads();

    short8 ah[2], al[2];
    #pragma unroll
    for (int mt = 0; mt < 2; ++mt) {
      int m = wave * 32 + mt * 16 + lrow;
      float4 f0 = *(const float4*)&Afl[m][q * 8];
      float4 f1 = *(const float4*)&Afl[m][q * 8 + 4];
      unsigned short h, l;
      split_bf(f0.x, h, l); ah[mt][0] = (short)h; al[mt][0] = (short)l;
      split_bf(f0.y, h, l); ah[mt][1] = (short)h; al[mt][1] = (short)l;
      split_bf(f0.z, h, l); ah[mt][2] = (short)h; al[mt][2] = (short)l;
      split_bf(f0.w, h, l); ah[mt][3] = (short)h; al[mt][3] = (short)l;
      split_bf(f1.x, h, l); ah[mt][4] = (short)h; al[mt][4] = (short)l;
      split_bf(f1.y, h, l); ah[mt][5] = (short)h; al[mt][5] = (short)l;
      split_bf(f1.z, h, l); ah[mt][6] = (short)h; al[mt][6] = (short)l;
      split_bf(f1.w, h, l); ah[mt][7] = (short)h; al[mt][7] = (short)l;
    }

    #pragma unroll
    for (int nt = 0; nt < 8; ++nt) {
      int j = nt * 16 + lrow;
      short8 bh = *(const short8*)&WldsH[j][q * 8];
      short8 bl = *(const short8*)&WldsL[j][q * 8];
      #pragma unroll
      for (int mt = 0; mt < 2; ++mt) {
        acc1[mt][nt] = __builtin_amdgcn_mfma_f32_16x16x32_bf16(ah[mt], bh, acc1[mt][nt], 0, 0, 0);
        acc1[mt][nt] = __builtin_amdgcn_mfma_f32_16x16x32_bf16(al[mt], bh, acc1[mt][nt], 0, 0, 0);
        acc1[mt][nt] = __builtin_amdgcn_mfma_f32_16x16x32_bf16(ah[mt], bl, acc1[mt][nt], 0, 0, 0);
      }
    }

    if (WITH_V) {
      __syncthreads();   // all waves done reading W1 slice
      #pragma unroll
      for (int u = 0; u < 4; ++u) {
        int idx = tid + u * 256;
        int half = idx >> 9, rem = idx & 511;
        int j = rem >> 2, seg = rem & 3;
        const unsigned short* src = (half ? Wvl : Wvh) + j * 128 + ks * 32 + seg * 8;
        short8 v = *(const short8*)src;
        unsigned short* dst = (half ? &WldsL[j][seg * 8] : &WldsH[j][seg * 8]);
        *(short8*)dst = v;
      }
      __syncthreads();
      #pragma unroll
      for (int nt = 0; nt < 8; ++nt) {
        int j = nt * 16 + lrow;
        short8 ch = *(const short8*)&WldsH[j][q * 8];
        short8 cl = *(const short8*)&WldsL[j][q * 8];
        #pragma unroll
        for (int mt = 0; mt < 2; ++mt) {
          accv[mt][nt] = __builtin_amdgcn_mfma_f32_16x16x32_bf16(ah[mt], ch, accv[mt][nt], 0, 0, 0);
          accv[mt][nt] = __builtin_amdgcn_mfma_f32_16x16x32_bf16(al[mt], ch, accv[mt][nt], 0, 0, 0);
          accv[mt][nt] = __builtin_amdgcn_mfma_f32_16x16x32_bf16(ah[mt], cl, accv[mt][nt], 0, 0, 0);
        }
      }
    }
  }

  // ---- V epilogue (bf16 seq order) ----
  if (WITH_V) {
    #pragma unroll
    for (int mt = 0; mt < 2; ++mt)
      #pragma unroll
      for (int reg = 0; reg < 4; ++reg) {
        int t = t0 + wave * 32 + mt * 16 + q * 4 + reg;
        size_t ro = (size_t)seqmap[t] * 128;
        #pragma unroll
        for (int nt = 0; nt < 8; ++nt) {
          int j = nt * 16 + lrow;
          Voh[ro + j] = f2bf_rne(accv[mt][nt][reg] + bv[j]);
        }
      }
  }

  // ---- stage 2: O = (relu(acc1 + b1) @ W2^T + b2) * postscale ----
  f32x4 acc2[2][8];
  #pragma unroll
  for (int mt = 0; mt < 2; ++mt)
    #pragma unroll
    for (int nt = 0; nt < 8; ++nt) acc2[mt][nt] = (f32x4){0.f, 0.f, 0.f, 0.f};

  float b1v[8];
  #pragma unroll
  for (int nt = 0; nt < 8; ++nt) b1v[nt] = b1[nt * 16 + lrow];

  #pragma unroll
  for (int ks2 = 0; ks2 < 4; ++ks2) {
    __syncthreads();   // previous overlay reads done (incl. stage-1 last iter)
    #pragma unroll
    for (int u = 0; u < 4; ++u) {
      int idx = tid + u * 256;
      int half = idx >> 9, rem = idx & 511;
      int j = rem >> 2, seg = rem & 3;
      const unsigned short* src = (half ? W2l : W2h) + j * 128 + ks2 * 32 + seg * 8;
      short8 v = *(const short8*)src;
      unsigned short* dst = (half ? &W2ldsL[j][seg * 8] : &W2ldsH[j][seg * 8]);
      *(short8*)dst = v;
    }
    // H k-slice: registers (C/D layout) -> LDS A-slice (split hi/lo)
    #pragma unroll
    for (int mt = 0; mt < 2; ++mt) {
      #pragma unroll
      for (int n2 = 0; n2 < 2; ++n2) {
        const int nt = ks2 * 2 + n2;
        #pragma unroll
        for (int reg = 0; reg < 4; ++reg) {
          int row = wave * 32 + mt * 16 + q * 4 + reg;
          float v = fmaxf(acc1[mt][nt][reg] + b1v[nt], 0.f);
          unsigned short h, l;
          split_bf(v, h, l);
          AshH[row][n2 * 16 + lrow] = h;
          AshL[row][n2 * 16 + lrow] = l;
        }
      }
    }
    __syncthreads();

    short8 ah[2], al[2];
    #pragma unroll
    for (int mt = 0; mt < 2; ++mt) {
      int m = wave * 32 + mt * 16 + lrow;
      ah[mt] = *(const short8*)&AshH[m][q * 8];
      al[mt] = *(const short8*)&AshL[m][q * 8];
    }
    #pragma unroll
    for (int nt = 0; nt < 8; ++nt) {
      int j = nt * 16 + lrow;
      short8 bh = *(const short8*)&W2ldsH[j][q * 8];
      short8 bl = *(const short8*)&W2ldsL[j][q * 8];
      #pragma unroll
      for (int mt = 0; mt < 2; ++mt) {
        acc2[mt][nt] = __builtin_amdgcn_mfma_f32_16x16x32_bf16(ah[mt], bh, acc2[mt][nt], 0, 0, 0);
        acc2[mt][nt] = __builtin_amdgcn_mfma_f32_16x16x32_bf16(al[mt], bh, acc2[mt][nt], 0, 0, 0);
        acc2[mt][nt] = __builtin_amdgcn_mfma_f32_16x16x32_bf16(ah[mt], bl, acc2[mt][nt], 0, 0, 0);
      }
    }
  }

  // ---- O epilogue (split-bf16, seq order) ----
  #pragma unroll
  for (int mt = 0; mt < 2; ++mt)
    #pragma unroll
    for (int reg = 0; reg < 4; ++reg) {
      int t = t0 + wave * 32 + mt * 16 + q * 4 + reg;
      size_t ro = (size_t)seqmap[t] * 128;
      #pragma unroll
      for (int nt = 0; nt < 8; ++nt) {
        int j = nt * 16 + lrow;
        float v = (acc2[mt][nt][reg] + b2[j]) * postscale;
        unsigned short h, l;
        split_bf(v, h, l);
        Oh[ro + j] = h;
        Ol[ro + j] = l;
      }
    }
}

// Flash attention, swapped-operand form: grid (NB, 6), 4 waves = 4 heads, 32 q/block.
// S^T = mfma(K, Q): lane holds query = lane&15, keys = s*16 + quad*4 + r4.
// Softmax reduce over keys = 7 in-lane ops + 2 shfl (xor16, xor32).
// P -> PV B-frag transpose via packed u32 LDS (b64 writes, b128 reads).
// PV: O^T = mfma(A=V^T, B=P); ctx stored as aligned float4 per dim-quad.
__global__ __launch_bounds__(256, 4)
void k_flash(const unsigned short* __restrict__ Qh, const unsigned short* __restrict__ Ql,
             const unsigned short* __restrict__ Kh, const unsigned short* __restrict__ Kl,
             const unsigned short* __restrict__ Vb, const int* __restrict__ start,
             float* __restrict__ ctx) {
  __shared__ unsigned short Vlds[32][134];            // 8576 B, odd-word row stride
  __shared__ alignas(16) unsigned PtH[4][32][20];     // [wave][query][key-pair] 10240 B
  __shared__ alignas(16) unsigned PtL[4][32][20];     // 10240 B
  const int g = blockIdx.x;
  const int tid = threadIdx.x;
  const int wv = tid >> 6;        // head
  const int lane = tid & 63;
  const int lrow = lane & 15;
  const int quad = lane >> 4;
  const int s0 = start[g];
  const int c = start[g + 1] - s0 + 1;   // slots incl. metal at 0
  const int sbase = s0 + g;
  const int hoff = wv * 32 + quad * 8;   // k-dim offset for frags

  for (int qb = 32 * blockIdx.y; qb < c; qb += 32 * gridDim.y) {
    short8 qfh[2], qfl[2];
    #pragma unroll
    for (int mt = 0; mt < 2; ++mt) {
      int qs = qb + mt * 16 + lrow; if (qs >= c) qs = 0;
      size_t off = (size_t)(sbase + qs) * 128 + hoff;
      qfh[mt] = *(const short8*)(Qh + off);
      qfl[mt] = *(const short8*)(Ql + off);
    }
    float mr[2], lr[2];
    f32x4 O[2][2];   // [mt][nt]: O^T tile, lane: query=lrow, dim=nt*16+quad*4+reg
    #pragma unroll
    for (int mt = 0; mt < 2; ++mt) {
      mr[mt] = -3.0e38f; lr[mt] = 0.f;
      O[mt][0] = (f32x4){0.f, 0.f, 0.f, 0.f};
      O[mt][1] = (f32x4){0.f, 0.f, 0.f, 0.f};
    }

    const int nch = (c + 31) >> 5;
    for (int ch = 0; ch < nch; ++ch) {
      const int kb = ch * 32;
      // K A-frags from global (row = key = lane&15)
      short8 kfh[2], kfl[2];
      #pragma unroll
      for (int s = 0; s < 2; ++s) {
        int ks = kb + s * 16 + lrow; if (ks >= c) ks = 0;
        size_t off = (size_t)(sbase + ks) * 128 + hoff;
        kfh[s] = *(const short8*)(Kh + off);
        kfl[s] = *(const short8*)(Kl + off);
      }
      __syncthreads();   // previous chunk's Vlds reads complete
      // stage V chunk (32 keys x 128 dims bf16), row-major, odd-word stride
      #pragma unroll
      for (int r = 0; r < 2; ++r) {
        int key = r * 16 + (tid >> 4);
        int seg = tid & 15;
        int ks = kb + key; if (ks >= c) ks = 0;
        uint4 v = *(const uint4*)(Vb + (size_t)(sbase + ks) * 128 + seg * 8);
        unsigned* dst = (unsigned*)&Vlds[key][seg * 8];   // 4B-aligned
        dst[0] = v.x; dst[1] = v.y; dst[2] = v.z; dst[3] = v.w;
      }
      __syncthreads();

      // S^T = K Q^T (split-bf16, 3 MFMA per tile). sv[mt][s]: rows=keys, cols=queries
      f32x4 sv[2][2];
      #pragma unroll
      for (int mt = 0; mt < 2; ++mt)
        #pragma unroll
        for (int s = 0; s < 2; ++s) {
          f32x4 z = (f32x4){0.f, 0.f, 0.f, 0.f};
          z = __builtin_amdgcn_mfma_f32_16x16x32_bf16(kfh[s], qfh[mt], z, 0, 0, 0);
          z = __builtin_amdgcn_mfma_f32_16x16x32_bf16(kfl[s], qfh[mt], z, 0, 0, 0);
          z = __builtin_amdgcn_mfma_f32_16x16x32_bf16(kfh[s], qfl[mt], z, 0, 0, 0);
          sv[mt][s] = z;
        }

      #pragma unroll
      for (int mt = 0; mt < 2; ++mt) {
        // mask + in-lane max over 8 keys held by this lane
        float m8 = mr[mt];
        #pragma unroll
        for (int s = 0; s < 2; ++s)
          #pragma unroll
          for (int r4 = 0; r4 < 4; ++r4) {
            bool valid = (kb + s * 16 + quad * 4 + r4) < c;
            float v = valid ? sv[mt][s][r4] : -3.0e38f;
            sv[mt][s][r4] = v;
            m8 = fmaxf(m8, v);
          }
        m8 = fmaxf(m8, __shfl_xor(m8, 16));
        m8 = fmaxf(m8, __shfl_xor(m8, 32));
        float al = exp2f(mr[mt] - m8);
        mr[mt] = m8;

        float p[2][4];
        float rs = 0.f;
        #pragma unroll
        for (int s = 0; s < 2; ++s)
          #pragma unroll
          for (int r4 = 0; r4 < 4; ++r4) {
            p[s][r4] = exp2f(sv[mt][s][r4] - m8);
            rs += p[s][r4];
          }
        rs += __shfl_xor(rs, 16);
        rs += __shfl_xor(rs, 32);
        lr[mt] = lr[mt] * al + rs;

        // split + pack + store P^T (wave-private; same-wave read below)
        const int Q = mt * 16 + lrow;
        #pragma unroll
        for (int s = 0; s < 2; ++s) {
          unsigned short h0, l0, h1, l1, h2, l2, h3, l3;
          split_bf(p[s][0], h0, l0); split_bf(p[s][1], h1, l1);
          split_bf(p[s][2], h2, l2); split_bf(p[s][3], h3, l3);
          uint2 hw, lw;
          hw.x = (unsigned)h0 | ((unsigned)h1 << 16);
          hw.y = (unsigned)h2 | ((unsigned)h3 << 16);
          lw.x = (unsigned)l0 | ((unsigned)l1 << 16);
          lw.y = (unsigned)l2 | ((unsigned)l3 << 16);
          *(uint2*)&PtH[wv][Q][s * 8 + quad * 2] = hw;
          *(uint2*)&PtL[wv][Q][s * 8 + quad * 2] = lw;
        }
        // O rescale
        #pragma unroll
        for (int nt = 0; nt < 2; ++nt)
          #pragma unroll
          for (int r4 = 0; r4 < 4; ++r4)
            O[mt][nt][r4] *= al;
      }

      // V A-frags (transposed Vlds access): A[dim][key], row=dim=lane&15
      short8 vf[2];
      #pragma unroll
      for (int nt = 0; nt < 2; ++nt)
        #pragma unroll
        for (int jj = 0; jj < 8; ++jj)
          vf[nt][jj] = (short)Vlds[quad * 8 + jj][wv * 32 + nt * 16 + lrow];

      // PV: O^T += V^T (Ph + Pl)
      #pragma unroll
      for (int mt = 0; mt < 2; ++mt) {
        short8 bh = *(const short8*)&PtH[wv][mt * 16 + lrow][quad * 4];
        short8 bl = *(const short8*)&PtL[wv][mt * 16 + lrow][quad * 4];
        #pragma unroll
        for (int nt = 0; nt < 2; ++nt) {
          O[mt][nt] = __builtin_amdgcn_mfma_f32_16x16x32_bf16(vf[nt], bh, O[mt][nt], 0, 0, 0);
          O[mt][nt] = __builtin_amdgcn_mfma_f32_16x16x32_bf16(vf[nt], bl, O[mt][nt], 0, 0, 0);
        }
      }
    }

    // store ctx (fp32, seq order). Lane: query = lrow, dims = nt*16 + quad*4 + r4
    #pragma unroll
    for (int mt = 0; mt < 2; ++mt) {
      int qs = qb + mt * 16 + lrow;
      if (qs < c) {
        float inv = 1.f / lr[mt];
        float* cp = ctx + (size_t)(sbase + qs) * 128 + wv * 32 + quad * 4;
        float4 o0, o1;
        o0.x = O[mt][0][0] * inv; o0.y = O[mt][0][1] * inv;
        o0.z = O[mt][0][2] * inv; o0.w = O[mt][0][3] * inv;
        o1.x = O[mt][1][0] * inv; o1.y = O[mt][1][1] * inv;
        o1.z = O[mt][1][2] * inv; o1.w = O[mt][1][3] * inv;
        *(float4*)cp = o0;
        *(float4*)(cp + 16) = o1;
      }
    }
  }
}

extern "C" void kernel_launch(void* const* d_in, const int* in_sizes, int n_in,
                              void* d_out, int out_size, void* d_ws, size_t ws_size,
                              hipStream_t stream) {
  const float* x       = (const float*)d_in[0];
  const float* metal_x = (const float*)d_in[1];
  const int*   batch   = (const int*)d_in[2];
  const float* Wk      = (const float*)d_in[3];
  const float* bk      = (const float*)d_in[4];
  const float* Wq      = (const float*)d_in[5];
  const float* bq      = (const float*)d_in[6];
  const float* in_w    = (const float*)d_in[7];
  const float* in_b    = (const float*)d_in[8];
  const float* out_w   = (const float*)d_in[9];
  const float* out_b   = (const float*)d_in[10];
  float* out = (float*)d_out;

  // ---- workspace layout (float offsets) ----
  // [0,528)            start (513 ints, padded)
  // [528,66576)        seqmap (66048 ints)
  // [66576,164880)     Wh+Wl  (2 x 98304 shorts)
  // [164880, ...)      big buffers
  float* ws = (float*)d_ws;
  int* start  = (int*)d_ws;
  int* seqmap = (int*)(ws + 528);
  unsigned short* Wh = (unsigned short*)(ws + 66576);
  unsigned short* Wl = Wh + 768 * 128;
  const size_t BUF0 = 164880;
  float* ctx = ws + BUF0;                                        // TE floats
  unsigned short* Qsh = (unsigned short*)(ws + BUF0 + TE);
  unsigned short* Qsl = Qsh + TE;
  unsigned short* Ksh = (unsigned short*)(ws + BUF0 + 2 * TE);
  unsigned short* Ksl = Ksh + TE;
  unsigned short* Vsb = (unsigned short*)(ws + BUF0 + 3 * TE);   // bf16 only
  // peak ws = (164880 + 3.5*TE)*4 B ~= 119.0 MB (unchanged from known-good)

  k_starts<<<NN / 256, 256, 0, stream>>>(batch, start);
  k_seqmap<<<TT / 256, 256, 0, stream>>>(batch, start, seqmap);
  k_wconv<<<768 * 128 / 256, 256, 0, stream>>>(Wq, Wk, in_w, out_w, Wh, Wl);

  const int gb = TT / 128;  // 516
  const float SCL2 = 0.17677669529663687f * 1.4426950408889634f;  // scale*log2(e)

  // x -> {V (bf16 seq), Hq -> Q (split seq, scaled)} in one pass over x
  k_fused<true><<<gb, 256, 0, stream>>>(
      x, metal_x,
      Wh, Wl, bq,                                  // W1 = Wq (relu)
      Wh + 512 * 128, Wl + 512 * 128, in_b + 2 * E, // Wv / bv
      Wh + 256 * 128, Wl + 256 * 128, in_b, SCL2,   // W2 = in_w q-proj
      Vsb, Qsh, Qsl, seqmap);
  // x -> Hk -> K (split seq)
  k_fused<false><<<gb, 256, 0, stream>>>(
      x, metal_x,
      Wh + 128 * 128, Wl + 128 * 128, bk,           // W1 = Wk (relu)
      nullptr, nullptr, nullptr,
      Wh + 384 * 128, Wl + 384 * 128, in_b + 128, 1.f, // W2 = in_w k-proj
      nullptr, Ksh, Ksl, seqmap);

  dim3 agrid(NB, 6);
  k_flash<<<agrid, 256, 0, stream>>>(Qsh, Qsl, Ksh, Ksl, Vsb, start, ctx);

  // out = ctx@out_w^T + b (A gathered via seqmap), token-order output
  k_gemm<AF32, OF32T, false><<<gb, 256, 0, stream>>>(
      ctx, nullptr, seqmap, nullptr, nullptr, Wh + 640 * 128, Wl + 640 * 128,
      out_b, 1.f, out, out + (size_t)NN * E, nullptr, nullptr, nullptr);
}

// Round 5
// 218.990 us; speedup vs baseline: 1.8067x; 1.5195x over previous
//
#include <hip/hip_runtime.h>

#define E   128
#define HD  32
#define NB  512
#define NN  65536
#define TT  (NB + NN)   // 66048 tokens: [0,NB) metal, [NB,TT) nodes
#define TE  ((size_t)TT * 128)

typedef __attribute__((ext_vector_type(8))) short short8;
typedef __attribute__((ext_vector_type(4))) float f32x4;

__device__ __forceinline__ const float* row_ptr(const float* base, const float* metal, int t) {
  return (t < NB) ? metal + (size_t)t * E : base + (size_t)(t - NB) * E;
}
__device__ __forceinline__ float* row_ptr_w(float* base, float* metal, int t) {
  return (t < NB) ? metal + (size_t)t * E : base + (size_t)(t - NB) * E;
}

__device__ __forceinline__ unsigned short f2bf_rne(float x) {
  unsigned u = __float_as_uint(x);
  return (unsigned short)((u + 0x7FFFu + ((u >> 16) & 1u)) >> 16);
}
__device__ __forceinline__ void split_bf(float x, unsigned short& h, unsigned short& l) {
  h = f2bf_rne(x);
  float hf = __uint_as_float(((unsigned)h) << 16);
  l = f2bf_rne(x - hf);
}

// start[b] = first node index of graph b (batch sorted); start[NB] = NN.
__global__ void k_starts(const int* __restrict__ batch, int* __restrict__ start) {
  int i = blockIdx.x * blockDim.x + threadIdx.x;
  if (i >= NN) return;
  int bi = batch[i];
  int bp = (i == 0) ? -1 : batch[i - 1];
  for (int b = bp + 1; b <= bi; ++b) start[b] = i;
  if (i == NN - 1)
    for (int b = bi + 1; b <= NB; ++b) start[b] = NN;
}

// seq row of token t: metal g -> start[g]+g ; node i -> i + batch[i] + 1
__global__ void k_seqmap(const int* __restrict__ batch, const int* __restrict__ start,
                         int* __restrict__ seqmap) {
  int t = blockIdx.x * 256 + threadIdx.x;
  if (t >= TT) return;
  seqmap[t] = (t < NB) ? (start[t] + t) : (t - NB + batch[t - NB] + 1);
}

// Split weights to hi/lo bf16. Rows: [0,128)Wq | [128,256)Wk | [256,640)in_w | [640,768)out_w
__global__ void k_wconv(const float* __restrict__ Wq, const float* __restrict__ Wk,
                        const float* __restrict__ in_w, const float* __restrict__ out_w,
                        unsigned short* __restrict__ Wh, unsigned short* __restrict__ Wl) {
  int idx = blockIdx.x * 256 + threadIdx.x;
  int r = idx >> 7, c = idx & 127;
  float v;
  if (r < 128)      v = Wq[r * 128 + c];
  else if (r < 256) v = Wk[(r - 128) * 128 + c];
  else if (r < 640) v = in_w[(r - 256) * 128 + c];
  else              v = out_w[(r - 640) * 128 + c];
  unsigned short h, l;
  split_bf(v, h, l);
  Wh[idx] = h;
  Wl[idx] = l;
}

// out = ctx@out_w^T + b via split-bf16 MFMA. 128x128 tile, 4 waves. A gathered
// via seqmap (fp32 ctx), fp32 token-order output. (Round-2-proven k_gemm body.)
__global__ __launch_bounds__(256, 2)
void k_outproj(const float* __restrict__ Ax, const int* __restrict__ rowmap,
               const unsigned short* __restrict__ Wh, const unsigned short* __restrict__ Wl,
               const float* __restrict__ bias,
               float* __restrict__ Cx, float* __restrict__ Cm) {
  __shared__ char smem[40960];
  float (*Afl)[36] = (float (*)[36])smem;                               // 18432 B
  unsigned short (*WldsH)[40] = (unsigned short (*)[40])(smem + 20480);
  unsigned short (*WldsL)[40] = (unsigned short (*)[40])(smem + 30720);

  const int tid = threadIdx.x;
  const int wave = tid >> 6;
  const int lane = tid & 63;
  const int lrow = lane & 15;
  const int q = lane >> 4;
  const int t0 = blockIdx.x * 128;

  f32x4 acc[2][8];
  #pragma unroll
  for (int mt = 0; mt < 2; ++mt)
    #pragma unroll
    for (int nt = 0; nt < 8; ++nt) acc[mt][nt] = (f32x4){0.f, 0.f, 0.f, 0.f};

  for (int ks = 0; ks < 4; ++ks) {
    __syncthreads();
    #pragma unroll
    for (int u = 0; u < 4; ++u) {
      int e4 = tid + u * 256;
      int m = e4 >> 3, k4 = e4 & 7;
      const float* rp = Ax + (size_t)rowmap[t0 + m] * E;
      float4 v = ((const float4*)(rp + ks * 32))[k4];
      *(float4*)&Afl[m][k4 * 4] = v;
    }
    #pragma unroll
    for (int u = 0; u < 4; ++u) {
      int idx = tid + u * 256;
      int half = idx >> 9, rem = idx & 511;
      int j = rem >> 2, seg = rem & 3;
      const unsigned short* src = (half ? Wl : Wh) + j * 128 + ks * 32 + seg * 8;
      short8 v = *(const short8*)src;
      unsigned short* dst = (half ? &WldsL[j][seg * 8] : &WldsH[j][seg * 8]);
      *(short8*)dst = v;
    }
    __syncthreads();

    short8 ah[2], al[2];
    #pragma unroll
    for (int mt = 0; mt < 2; ++mt) {
      int m = wave * 32 + mt * 16 + lrow;
      float4 f0 = *(const float4*)&Afl[m][q * 8];
      float4 f1 = *(const float4*)&Afl[m][q * 8 + 4];
      unsigned short h, l;
      split_bf(f0.x, h, l); ah[mt][0] = (short)h; al[mt][0] = (short)l;
      split_bf(f0.y, h, l); ah[mt][1] = (short)h; al[mt][1] = (short)l;
      split_bf(f0.z, h, l); ah[mt][2] = (short)h; al[mt][2] = (short)l;
      split_bf(f0.w, h, l); ah[mt][3] = (short)h; al[mt][3] = (short)l;
      split_bf(f1.x, h, l); ah[mt][4] = (short)h; al[mt][4] = (short)l;
      split_bf(f1.y, h, l); ah[mt][5] = (short)h; al[mt][5] = (short)l;
      split_bf(f1.z, h, l); ah[mt][6] = (short)h; al[mt][6] = (short)l;
      split_bf(f1.w, h, l); ah[mt][7] = (short)h; al[mt][7] = (short)l;
    }

    #pragma unroll
    for (int nt = 0; nt < 8; ++nt) {
      int j = nt * 16 + lrow;
      short8 bh = *(const short8*)&WldsH[j][q * 8];
      short8 bl = *(const short8*)&WldsL[j][q * 8];
      #pragma unroll
      for (int mt = 0; mt < 2; ++mt) {
        acc[mt][nt] = __builtin_amdgcn_mfma_f32_16x16x32_bf16(ah[mt], bh, acc[mt][nt], 0, 0, 0);
        acc[mt][nt] = __builtin_amdgcn_mfma_f32_16x16x32_bf16(al[mt], bh, acc[mt][nt], 0, 0, 0);
        acc[mt][nt] = __builtin_amdgcn_mfma_f32_16x16x32_bf16(ah[mt], bl, acc[mt][nt], 0, 0, 0);
      }
    }
  }

  #pragma unroll
  for (int mt = 0; mt < 2; ++mt) {
    #pragma unroll
    for (int reg = 0; reg < 4; ++reg) {
      int t = t0 + wave * 32 + mt * 16 + q * 4 + reg;
      float* cp = row_ptr_w(Cx, Cm, t);
      #pragma unroll
      for (int nt = 0; nt < 8; ++nt) {
        int j = nt * 16 + lrow;
        cp[j] = acc[mt][nt][reg] + bias[j];
      }
    }
  }
}

// Merged projection kernel: 3*516 blocks, group = blockIdx.x % 3.
//   group 0: x -> Hq=relu(x@Wq^T+bq) -> Q=(Hq@Wiq^T+b)*SCL2  (split-bf16 seq)
//   group 1: x -> Hk=relu(x@Wk^T+bk) -> K= Hk@Wik^T+b        (split-bf16 seq)
//   group 2: x -> V = x@Wiv^T+b                               (bf16 seq)
// Stage 1 is the shared x@W^T body (round-2 k_fused). Groups 0/1 run the
// round-2 stage-2 body (reg->LDS transpose hand-off). All paths: 40960 B LDS,
// (256,2) bounds -> no spills. Heterogeneous block pool overlaps the three
// latency-bound pipelines in one dispatch.
__global__ __launch_bounds__(256, 2)
void k_mega(const float* __restrict__ x, const float* __restrict__ metal_x,
            const unsigned short* __restrict__ Wh, const unsigned short* __restrict__ Wl,
            const float* __restrict__ bq, const float* __restrict__ bk,
            const float* __restrict__ in_b, float scl2,
            unsigned short* __restrict__ Voh,
            unsigned short* __restrict__ Qsh, unsigned short* __restrict__ Qsl,
            unsigned short* __restrict__ Ksh, unsigned short* __restrict__ Ksl,
            const int* __restrict__ seqmap) {
  __shared__ char smem[40960];
  // stage-1 overlay
  float (*Afl)[36] = (float (*)[36])smem;                                   // 18432 B
  unsigned short (*WldsH)[40] = (unsigned short (*)[40])(smem + 18432);     // 10240 B
  unsigned short (*WldsL)[40] = (unsigned short (*)[40])(smem + 28672);     // 10240 B
  // stage-2 overlay (separated from stage-1 by __syncthreads)
  unsigned short (*AshH)[40] = (unsigned short (*)[40])smem;
  unsigned short (*AshL)[40] = (unsigned short (*)[40])(smem + 10240);
  unsigned short (*W2ldsH)[40] = (unsigned short (*)[40])(smem + 20480);
  unsigned short (*W2ldsL)[40] = (unsigned short (*)[40])(smem + 30720);

  const int tid = threadIdx.x;
  const int wave = tid >> 6;
  const int lane = tid & 63;
  const int lrow = lane & 15;
  const int q = lane >> 4;
  const int group = (int)(blockIdx.x % 3);
  const int t0 = (int)(blockIdx.x / 3) * 128;

  // stage-1 weight: g0 Wq (rows 0), g1 Wk (rows 128), g2 in_w V-proj (rows 512)
  const int w1o = (group == 0) ? 0 : (group == 1) ? 128 * 128 : 512 * 128;
  const unsigned short* W1h = Wh + w1o;
  const unsigned short* W1l = Wl + w1o;

  f32x4 acc1[2][8];
  #pragma unroll
  for (int mt = 0; mt < 2; ++mt)
    #pragma unroll
    for (int nt = 0; nt < 8; ++nt) acc1[mt][nt] = (f32x4){0.f, 0.f, 0.f, 0.f};

  // ---- stage 1: x tile -> acc1 ----
  for (int ks = 0; ks < 4; ++ks) {
    __syncthreads();
    #pragma unroll
    for (int u = 0; u < 4; ++u) {
      int e4 = tid + u * 256;
      int m = e4 >> 3, k4 = e4 & 7;
      const float* rp = row_ptr(x, metal_x, t0 + m);
      float4 v = ((const float4*)(rp + ks * 32))[k4];
      *(float4*)&Afl[m][k4 * 4] = v;
    }
    #pragma unroll
    for (int u = 0; u < 4; ++u) {
      int idx = tid + u * 256;
      int half = idx >> 9, rem = idx & 511;
      int j = rem >> 2, seg = rem & 3;
      const unsigned short* src = (half ? W1l : W1h) + j * 128 + ks * 32 + seg * 8;
      short8 v = *(const short8*)src;
      unsigned short* dst = (half ? &WldsL[j][seg * 8] : &WldsH[j][seg * 8]);
      *(short8*)dst = v;
    }
    __syncthreads();

    short8 ah[2], al[2];
    #pragma unroll
    for (int mt = 0; mt < 2; ++mt) {
      int m = wave * 32 + mt * 16 + lrow;
      float4 f0 = *(const float4*)&Afl[m][q * 8];
      float4 f1 = *(const float4*)&Afl[m][q * 8 + 4];
      unsigned short h, l;
      split_bf(f0.x, h, l); ah[mt][0] = (short)h; al[mt][0] = (short)l;
      split_bf(f0.y, h, l); ah[mt][1] = (short)h; al[mt][1] = (short)l;
      split_bf(f0.z, h, l); ah[mt][2] = (short)h; al[mt][2] = (short)l;
      split_bf(f0.w, h, l); ah[mt][3] = (short)h; al[mt][3] = (short)l;
      split_bf(f1.x, h, l); ah[mt][4] = (short)h; al[mt][4] = (short)l;
      split_bf(f1.y, h, l); ah[mt][5] = (short)h; al[mt][5] = (short)l;
      split_bf(f1.z, h, l); ah[mt][6] = (short)h; al[mt][6] = (short)l;
      split_bf(f1.w, h, l); ah[mt][7] = (short)h; al[mt][7] = (short)l;
    }

    #pragma unroll
    for (int nt = 0; nt < 8; ++nt) {
      int j = nt * 16 + lrow;
      short8 bh = *(const short8*)&WldsH[j][q * 8];
      short8 bl = *(const short8*)&WldsL[j][q * 8];
      #pragma unroll
      for (int mt = 0; mt < 2; ++mt) {
        acc1[mt][nt] = __builtin_amdgcn_mfma_f32_16x16x32_bf16(ah[mt], bh, acc1[mt][nt], 0, 0, 0);
        acc1[mt][nt] = __builtin_amdgcn_mfma_f32_16x16x32_bf16(al[mt], bh, acc1[mt][nt], 0, 0, 0);
        acc1[mt][nt] = __builtin_amdgcn_mfma_f32_16x16x32_bf16(ah[mt], bl, acc1[mt][nt], 0, 0, 0);
      }
    }
  }

  // ---- group 2: V epilogue (bf16 seq order), done ----
  if (group == 2) {
    const float* bv = in_b + 2 * E;
    #pragma unroll
    for (int mt = 0; mt < 2; ++mt)
      #pragma unroll
      for (int reg = 0; reg < 4; ++reg) {
        int t = t0 + wave * 32 + mt * 16 + q * 4 + reg;
        size_t ro = (size_t)seqmap[t] * 128;
        #pragma unroll
        for (int nt = 0; nt < 8; ++nt) {
          int j = nt * 16 + lrow;
          Voh[ro + j] = f2bf_rne(acc1[mt][nt][reg] + bv[j]);
        }
      }
    return;
  }

  // ---- groups 0/1: stage 2 ----
  const int w2o = (group == 0) ? 256 * 128 : 384 * 128;
  const unsigned short* W2h = Wh + w2o;
  const unsigned short* W2l = Wl + w2o;
  const float* b1 = (group == 0) ? bq : bk;
  const float* b2 = (group == 0) ? in_b : in_b + 128;
  const float postscale = (group == 0) ? scl2 : 1.f;
  unsigned short* Oh = (group == 0) ? Qsh : Ksh;
  unsigned short* Ol = (group == 0) ? Qsl : Ksl;

  f32x4 acc2[2][8];
  #pragma unroll
  for (int mt = 0; mt < 2; ++mt)
    #pragma unroll
    for (int nt = 0; nt < 8; ++nt) acc2[mt][nt] = (f32x4){0.f, 0.f, 0.f, 0.f};

  float b1v[8];
  #pragma unroll
  for (int nt = 0; nt < 8; ++nt) b1v[nt] = b1[nt * 16 + lrow];

  #pragma unroll
  for (int ks2 = 0; ks2 < 4; ++ks2) {
    __syncthreads();   // previous overlay reads done (incl. stage-1 last iter)
    #pragma unroll
    for (int u = 0; u < 4; ++u) {
      int idx = tid + u * 256;
      int half = idx >> 9, rem = idx & 511;
      int j = rem >> 2, seg = rem & 3;
      const unsigned short* src = (half ? W2l : W2h) + j * 128 + ks2 * 32 + seg * 8;
      short8 v = *(const short8*)src;
      unsigned short* dst = (half ? &W2ldsL[j][seg * 8] : &W2ldsH[j][seg * 8]);
      *(short8*)dst = v;
    }
    // H k-slice: registers (C/D layout) -> LDS A-slice (split hi/lo)
    #pragma unroll
    for (int mt = 0; mt < 2; ++mt) {
      #pragma unroll
      for (int n2 = 0; n2 < 2; ++n2) {
        const int nt = ks2 * 2 + n2;
        #pragma unroll
        for (int reg = 0; reg < 4; ++reg) {
          int row = wave * 32 + mt * 16 + q * 4 + reg;
          float v = fmaxf(acc1[mt][nt][reg] + b1v[nt], 0.f);
          unsigned short h, l;
          split_bf(v, h, l);
          AshH[row][n2 * 16 + lrow] = h;
          AshL[row][n2 * 16 + lrow] = l;
        }
      }
    }
    __syncthreads();

    short8 ah[2], al[2];
    #pragma unroll
    for (int mt = 0; mt < 2; ++mt) {
      int m = wave * 32 + mt * 16 + lrow;
      ah[mt] = *(const short8*)&AshH[m][q * 8];
      al[mt] = *(const short8*)&AshL[m][q * 8];
    }
    #pragma unroll
    for (int nt = 0; nt < 8; ++nt) {
      int j = nt * 16 + lrow;
      short8 bh = *(const short8*)&W2ldsH[j][q * 8];
      short8 bl = *(const short8*)&W2ldsL[j][q * 8];
      #pragma unroll
      for (int mt = 0; mt < 2; ++mt) {
        acc2[mt][nt] = __builtin_amdgcn_mfma_f32_16x16x32_bf16(ah[mt], bh, acc2[mt][nt], 0, 0, 0);
        acc2[mt][nt] = __builtin_amdgcn_mfma_f32_16x16x32_bf16(al[mt], bh, acc2[mt][nt], 0, 0, 0);
        acc2[mt][nt] = __builtin_amdgcn_mfma_f32_16x16x32_bf16(ah[mt], bl, acc2[mt][nt], 0, 0, 0);
      }
    }
  }

  // ---- O epilogue (split-bf16, seq order) ----
  #pragma unroll
  for (int mt = 0; mt < 2; ++mt)
    #pragma unroll
    for (int reg = 0; reg < 4; ++reg) {
      int t = t0 + wave * 32 + mt * 16 + q * 4 + reg;
      size_t ro = (size_t)seqmap[t] * 128;
      #pragma unroll
      for (int nt = 0; nt < 8; ++nt) {
        int j = nt * 16 + lrow;
        float v = (acc2[mt][nt][reg] + b2[j]) * postscale;
        unsigned short h, l;
        split_bf(v, h, l);
        Oh[ro + j] = h;
        Ol[ro + j] = l;
      }
    }
}

// Flash attention, swapped-operand form: grid (NB, 6), 4 waves = 4 heads, 32 q/block.
// S^T = mfma(K, Q): lane holds query = lane&15, keys = s*16 + quad*4 + r4.
// Softmax reduce over keys = 7 in-lane ops + 2 shfl (xor16, xor32).
// P -> PV B-frag transpose via packed u32 LDS (b64 writes, b128 reads).
// PV: O^T = mfma(A=V^T, B=P); ctx stored as aligned float4 per dim-quad.
__global__ __launch_bounds__(256, 4)
void k_flash(const unsigned short* __restrict__ Qh, const unsigned short* __restrict__ Ql,
             const unsigned short* __restrict__ Kh, const unsigned short* __restrict__ Kl,
             const unsigned short* __restrict__ Vb, const int* __restrict__ start,
             float* __restrict__ ctx) {
  __shared__ unsigned short Vlds[32][134];            // 8576 B, odd-word row stride
  __shared__ alignas(16) unsigned PtH[4][32][20];     // [wave][query][key-pair] 10240 B
  __shared__ alignas(16) unsigned PtL[4][32][20];     // 10240 B
  const int g = blockIdx.x;
  const int tid = threadIdx.x;
  const int wv = tid >> 6;        // head
  const int lane = tid & 63;
  const int lrow = lane & 15;
  const int quad = lane >> 4;
  const int s0 = start[g];
  const int c = start[g + 1] - s0 + 1;   // slots incl. metal at 0
  const int sbase = s0 + g;
  const int hoff = wv * 32 + quad * 8;   // k-dim offset for frags

  for (int qb = 32 * blockIdx.y; qb < c; qb += 32 * gridDim.y) {
    short8 qfh[2], qfl[2];
    #pragma unroll
    for (int mt = 0; mt < 2; ++mt) {
      int qs = qb + mt * 16 + lrow; if (qs >= c) qs = 0;
      size_t off = (size_t)(sbase + qs) * 128 + hoff;
      qfh[mt] = *(const short8*)(Qh + off);
      qfl[mt] = *(const short8*)(Ql + off);
    }
    float mr[2], lr[2];
    f32x4 O[2][2];   // [mt][nt]: O^T tile, lane: query=lrow, dim=nt*16+quad*4+reg
    #pragma unroll
    for (int mt = 0; mt < 2; ++mt) {
      mr[mt] = -3.0e38f; lr[mt] = 0.f;
      O[mt][0] = (f32x4){0.f, 0.f, 0.f, 0.f};
      O[mt][1] = (f32x4){0.f, 0.f, 0.f, 0.f};
    }

    const int nch = (c + 31) >> 5;
    for (int ch = 0; ch < nch; ++ch) {
      const int kb = ch * 32;
      // K A-frags from global (row = key = lane&15)
      short8 kfh[2], kfl[2];
      #pragma unroll
      for (int s = 0; s < 2; ++s) {
        int ks = kb + s * 16 + lrow; if (ks >= c) ks = 0;
        size_t off = (size_t)(sbase + ks) * 128 + hoff;
        kfh[s] = *(const short8*)(Kh + off);
        kfl[s] = *(const short8*)(Kl + off);
      }
      __syncthreads();   // previous chunk's Vlds reads complete
      // stage V chunk (32 keys x 128 dims bf16), row-major, odd-word stride
      #pragma unroll
      for (int r = 0; r < 2; ++r) {
        int key = r * 16 + (tid >> 4);
        int seg = tid & 15;
        int ks = kb + key; if (ks >= c) ks = 0;
        uint4 v = *(const uint4*)(Vb + (size_t)(sbase + ks) * 128 + seg * 8);
        unsigned* dst = (unsigned*)&Vlds[key][seg * 8];   // 4B-aligned
        dst[0] = v.x; dst[1] = v.y; dst[2] = v.z; dst[3] = v.w;
      }
      __syncthreads();

      // S^T = K Q^T (split-bf16, 3 MFMA per tile). sv[mt][s]: rows=keys, cols=queries
      f32x4 sv[2][2];
      #pragma unroll
      for (int mt = 0; mt < 2; ++mt)
        #pragma unroll
        for (int s = 0; s < 2; ++s) {
          f32x4 z = (f32x4){0.f, 0.f, 0.f, 0.f};
          z = __builtin_amdgcn_mfma_f32_16x16x32_bf16(kfh[s], qfh[mt], z, 0, 0, 0);
          z = __builtin_amdgcn_mfma_f32_16x16x32_bf16(kfl[s], qfh[mt], z, 0, 0, 0);
          z = __builtin_amdgcn_mfma_f32_16x16x32_bf16(kfh[s], qfl[mt], z, 0, 0, 0);
          sv[mt][s] = z;
        }

      #pragma unroll
      for (int mt = 0; mt < 2; ++mt) {
        // mask + in-lane max over 8 keys held by this lane
        float m8 = mr[mt];
        #pragma unroll
        for (int s = 0; s < 2; ++s)
          #pragma unroll
          for (int r4 = 0; r4 < 4; ++r4) {
            bool valid = (kb + s * 16 + quad * 4 + r4) < c;
            float v = valid ? sv[mt][s][r4] : -3.0e38f;
            sv[mt][s][r4] = v;
            m8 = fmaxf(m8, v);
          }
        m8 = fmaxf(m8, __shfl_xor(m8, 16));
        m8 = fmaxf(m8, __shfl_xor(m8, 32));
        float al = exp2f(mr[mt] - m8);
        mr[mt] = m8;

        float p[2][4];
        float rs = 0.f;
        #pragma unroll
        for (int s = 0; s < 2; ++s)
          #pragma unroll
          for (int r4 = 0; r4 < 4; ++r4) {
            p[s][r4] = exp2f(sv[mt][s][r4] - m8);
            rs += p[s][r4];
          }
        rs += __shfl_xor(rs, 16);
        rs += __shfl_xor(rs, 32);
        lr[mt] = lr[mt] * al + rs;

        // split + pack + store P^T (wave-private; same-wave read below)
        const int Q = mt * 16 + lrow;
        #pragma unroll
        for (int s = 0; s < 2; ++s) {
          unsigned short h0, l0, h1, l1, h2, l2, h3, l3;
          split_bf(p[s][0], h0, l0); split_bf(p[s][1], h1, l1);
          split_bf(p[s][2], h2, l2); split_bf(p[s][3], h3, l3);
          uint2 hw, lw;
          hw.x = (unsigned)h0 | ((unsigned)h1 << 16);
          hw.y = (unsigned)h2 | ((unsigned)h3 << 16);
          lw.x = (unsigned)l0 | ((unsigned)l1 << 16);
          lw.y = (unsigned)l2 | ((unsigned)l3 << 16);
          *(uint2*)&PtH[wv][Q][s * 8 + quad * 2] = hw;
          *(uint2*)&PtL[wv][Q][s * 8 + quad * 2] = lw;
        }
        // O rescale
        #pragma unroll
        for (int nt = 0; nt < 2; ++nt)
          #pragma unroll
          for (int r4 = 0; r4 < 4; ++r4)
            O[mt][nt][r4] *= al;
      }

      // V A-frags (transposed Vlds access): A[dim][key], row=dim=lane&15
      short8 vf[2];
      #pragma unroll
      for (int nt = 0; nt < 2; ++nt)
        #pragma unroll
        for (int jj = 0; jj < 8; ++jj)
          vf[nt][jj] = (short)Vlds[quad * 8 + jj][wv * 32 + nt * 16 + lrow];

      // PV: O^T += V^T (Ph + Pl)
      #pragma unroll
      for (int mt = 0; mt < 2; ++mt) {
        short8 bh = *(const short8*)&PtH[wv][mt * 16 + lrow][quad * 4];
        short8 bl = *(const short8*)&PtL[wv][mt * 16 + lrow][quad * 4];
        #pragma unroll
        for (int nt = 0; nt < 2; ++nt) {
          O[mt][nt] = __builtin_amdgcn_mfma_f32_16x16x32_bf16(vf[nt], bh, O[mt][nt], 0, 0, 0);
          O[mt][nt] = __builtin_amdgcn_mfma_f32_16x16x32_bf16(vf[nt], bl, O[mt][nt], 0, 0, 0);
        }
      }
    }

    // store ctx (fp32, seq order). Lane: query = lrow, dims = nt*16 + quad*4 + r4
    #pragma unroll
    for (int mt = 0; mt < 2; ++mt) {
      int qs = qb + mt * 16 + lrow;
      if (qs < c) {
        float inv = 1.f / lr[mt];
        float* cp = ctx + (size_t)(sbase + qs) * 128 + wv * 32 + quad * 4;
        float4 o0, o1;
        o0.x = O[mt][0][0] * inv; o0.y = O[mt][0][1] * inv;
        o0.z = O[mt][0][2] * inv; o0.w = O[mt][0][3] * inv;
        o1.x = O[mt][1][0] * inv; o1.y = O[mt][1][1] * inv;
        o1.z = O[mt][1][2] * inv; o1.w = O[mt][1][3] * inv;
        *(float4*)cp = o0;
        *(float4*)(cp + 16) = o1;
      }
    }
  }
}

extern "C" void kernel_launch(void* const* d_in, const int* in_sizes, int n_in,
                              void* d_out, int out_size, void* d_ws, size_t ws_size,
                              hipStream_t stream) {
  const float* x       = (const float*)d_in[0];
  const float* metal_x = (const float*)d_in[1];
  const int*   batch   = (const int*)d_in[2];
  const float* Wk      = (const float*)d_in[3];
  const float* bk      = (const float*)d_in[4];
  const float* Wq      = (const float*)d_in[5];
  const float* bq      = (const float*)d_in[6];
  const float* in_w    = (const float*)d_in[7];
  const float* in_b    = (const float*)d_in[8];
  const float* out_w   = (const float*)d_in[9];
  const float* out_b   = (const float*)d_in[10];
  float* out = (float*)d_out;

  // ---- workspace layout (float offsets) ----
  // [0,528)            start (513 ints, padded)
  // [528,66576)        seqmap (66048 ints)
  // [66576,164880)     Wh+Wl  (2 x 98304 shorts)
  // [164880, ...)      big buffers
  float* ws = (float*)d_ws;
  int* start  = (int*)d_ws;
  int* seqmap = (int*)(ws + 528);
  unsigned short* Wh = (unsigned short*)(ws + 66576);
  unsigned short* Wl = Wh + 768 * 128;
  const size_t BUF0 = 164880;
  float* ctx = ws + BUF0;                                        // TE floats
  unsigned short* Qsh = (unsigned short*)(ws + BUF0 + TE);
  unsigned short* Qsl = Qsh + TE;
  unsigned short* Ksh = (unsigned short*)(ws + BUF0 + 2 * TE);
  unsigned short* Ksl = Ksh + TE;
  unsigned short* Vsb = (unsigned short*)(ws + BUF0 + 3 * TE);   // bf16 only
  // peak ws = (164880 + 3.5*TE)*4 B ~= 119.0 MB (unchanged from known-good)

  k_starts<<<NN / 256, 256, 0, stream>>>(batch, start);
  k_seqmap<<<TT / 256, 256, 0, stream>>>(batch, start, seqmap);
  k_wconv<<<768 * 128 / 256, 256, 0, stream>>>(Wq, Wk, in_w, out_w, Wh, Wl);

  const int gb = TT / 128;  // 516
  const float SCL2 = 0.17677669529663687f * 1.4426950408889634f;  // scale*log2(e)

  // One dispatch for all three projection pipelines: {x->Hq->Q, x->Hk->K, x->V}
  k_mega<<<gb * 3, 256, 0, stream>>>(
      x, metal_x, Wh, Wl, bq, bk, in_b, SCL2,
      Vsb, Qsh, Qsl, Ksh, Ksl, seqmap);

  dim3 agrid(NB, 6);
  k_flash<<<agrid, 256, 0, stream>>>(Qsh, Qsl, Ksh, Ksl, Vsb, start, ctx);

  // out = ctx@out_w^T + b (A gathered via seqmap), token-order output
  k_outproj<<<gb, 256, 0, stream>>>(
      ctx, seqmap, Wh + 640 * 128, Wl + 640 * 128,
      out_b, out, out + (size_t)NN * E);
}